// Round 1
// baseline (223.167 us; speedup 1.0000x reference)
//
#include <hip/hip_runtime.h>
#include <hip/hip_bf16.h>

#define BB 128      // batch
#define SS 128      // seq len
#define VD 128      // VALUE_DIM
#define CN 64       // CONCEPT_NUM
#define KD 128      // KEY_DIM
#define QN 10000
#define MROWS (2*BB*SS)       // 32768
#define MTOT  (MROWS + BB)    // 32896
#define LDST 132              // padded LDS row stride (floats)

__device__ __forceinline__ float bflo(unsigned int u) { return __uint_as_float(u << 16); }
__device__ __forceinline__ float bfhi(unsigned int u) { return __uint_as_float(u & 0xffff0000u); }
__device__ __forceinline__ unsigned short f2bf(float f) {
    unsigned int x = __float_as_uint(f);
    return (unsigned short)((x + 0x7fffu + ((x >> 16) & 1u)) >> 16);
}

// ---------------- kernel 1: success/failure counts -> sigmoid ----------------
__global__ void k_count(const int* __restrict__ ri, const int* __restrict__ wi,
                        float* __restrict__ sig) {
    __shared__ int sr_s[4], sw_s[4];
    int t = threadIdx.x;
    int sr = 0, sw = 0;
    for (int i = t; i < BB*SS; i += 256) { sr += (ri[i] >= 1); sw += (wi[i] >= 1); }
    for (int off = 1; off < 64; off <<= 1) { sr += __shfl_xor(sr, off); sw += __shfl_xor(sw, off); }
    int wid = t >> 6;
    if ((t & 63) == 0) { sr_s[wid] = sr; sw_s[wid] = sw; }
    __syncthreads();
    if (t == 0) {
        int SR = sr_s[0]+sr_s[1]+sr_s[2]+sr_s[3];
        int SW = sw_s[0]+sw_s[1]+sw_s[2]+sw_s[3];
        sig[0] = 1.0f / (1.0f + __expf(-(float)SR));
        sig[1] = 1.0f / (1.0f + __expf(-(float)SW));
    }
}

// ---------------- kernel 2: precompute E, A (bf16) and W (bf16) / WT (f32) ----------------
__global__ __launch_bounds__(256) void k_pre(
    const int* __restrict__ ri, const int* __restrict__ wi, const int* __restrict__ tgt,
    const float* __restrict__ q_emb, const float* __restrict__ i_emb,
    const float* __restrict__ key_W,
    const float* __restrict__ erase_W, const float* __restrict__ erase_b,
    const float* __restrict__ add_W,   const float* __restrict__ add_b,
    unsigned short* __restrict__ Ebuf, unsigned short* __restrict__ Abuf,
    unsigned short* __restrict__ Wbuf, float* __restrict__ WTbuf)
{
    __shared__ float vec[64 * LDST];   // also reused as logits [64][65]
    __shared__ int   qid_s[64];
    __shared__ int   irow_s[64];
    __shared__ float inv_s[64];
    __shared__ float rmax_s[64];

    const int t = threadIdx.x;
    const int base = blockIdx.x * 64;

    if (t < 64) {
        int r = base + t;
        int qid, irow = -1;
        if (r < MROWS) {
            int m = r >> 14;
            int idx = r & 16383;
            int inter = (m == 0 ? ri[idx] : wi[idx]);
            irow = inter;
            qid = (inter > QN) ? (inter - QN) : inter;
        } else {
            qid = tgt[r - MROWS];
        }
        qid_s[t] = qid;
        irow_s[t] = irow;
    }
    __syncthreads();

    const int ty = t >> 4, tx = t & 15;
    const int r0 = ty * 4;

    const bool ea = (base < MROWS);
    if (ea) {
        // stage vec rows (row-major, padded)
        for (int p = 0; p < 8; ++p) {
            int row = p * 8 + (t >> 5);
            int kq  = t & 31;
            float4 src = *(const float4*)(i_emb + (size_t)irow_s[row] * KD + kq * 4);
            *(float4*)(vec + row * LDST + kq * 4) = src;
        }
        __syncthreads();

        for (int pass = 0; pass < 4; ++pass) {
            const bool is_e = (pass < 2);
            const int  cl   = (pass & 1) * 64 + tx * 4;     // local col 0..127
            const float* Wm = is_e ? erase_W : add_W;
            const float* bm = is_e ? erase_b : add_b;
            const float* w0 = Wm + (size_t)cl * KD;

            float acc[4][4];
            #pragma unroll
            for (int i = 0; i < 4; ++i)
                #pragma unroll
                for (int j = 0; j < 4; ++j) acc[i][j] = 0.0f;

            #pragma unroll 4
            for (int k4 = 0; k4 < 32; ++k4) {
                float4 av[4];
                #pragma unroll
                for (int rr = 0; rr < 4; ++rr)
                    av[rr] = *(const float4*)(vec + (r0 + rr) * LDST + k4 * 4);
                #pragma unroll
                for (int ci = 0; ci < 4; ++ci) {
                    float4 wv = *(const float4*)(w0 + (size_t)ci * KD + k4 * 4);
                    #pragma unroll
                    for (int rr = 0; rr < 4; ++rr) {
                        acc[rr][ci] = fmaf(av[rr].x, wv.x, acc[rr][ci]);
                        acc[rr][ci] = fmaf(av[rr].y, wv.y, acc[rr][ci]);
                        acc[rr][ci] = fmaf(av[rr].z, wv.z, acc[rr][ci]);
                        acc[rr][ci] = fmaf(av[rr].w, wv.w, acc[rr][ci]);
                    }
                }
            }
            #pragma unroll
            for (int rr = 0; rr < 4; ++rr) {
                int r = base + r0 + rr;
                ushort4 pk;
                unsigned short us[4];
                #pragma unroll
                for (int ci = 0; ci < 4; ++ci) {
                    float x = acc[rr][ci] + bm[cl + ci];
                    float y = is_e ? (1.0f / (1.0f + __expf(-x))) : tanhf(x);
                    us[ci] = f2bf(y);
                }
                pk.x = us[0]; pk.y = us[1]; pk.z = us[2]; pk.w = us[3];
                unsigned short* dst = (is_e ? Ebuf : Abuf) + (size_t)r * VD + cl;
                *(ushort4*)dst = pk;
            }
        }
        __syncthreads();
    }

    // stage qe rows (overwrites vec)
    for (int p = 0; p < 8; ++p) {
        int row = p * 8 + (t >> 5);
        int kq  = t & 31;
        float4 src = *(const float4*)(q_emb + (size_t)qid_s[row] * KD + kq * 4);
        *(float4*)(vec + row * LDST + kq * 4) = src;
    }
    __syncthreads();

    // key logits: 64 cols
    {
        const int c0 = tx * 4;
        const float* w0 = key_W + (size_t)c0 * KD;
        float acc[4][4];
        #pragma unroll
        for (int i = 0; i < 4; ++i)
            #pragma unroll
            for (int j = 0; j < 4; ++j) acc[i][j] = 0.0f;

        #pragma unroll 4
        for (int k4 = 0; k4 < 32; ++k4) {
            float4 av[4];
            #pragma unroll
            for (int rr = 0; rr < 4; ++rr)
                av[rr] = *(const float4*)(vec + (r0 + rr) * LDST + k4 * 4);
            #pragma unroll
            for (int ci = 0; ci < 4; ++ci) {
                float4 wv = *(const float4*)(w0 + (size_t)ci * KD + k4 * 4);
                #pragma unroll
                for (int rr = 0; rr < 4; ++rr) {
                    acc[rr][ci] = fmaf(av[rr].x, wv.x, acc[rr][ci]);
                    acc[rr][ci] = fmaf(av[rr].y, wv.y, acc[rr][ci]);
                    acc[rr][ci] = fmaf(av[rr].z, wv.z, acc[rr][ci]);
                    acc[rr][ci] = fmaf(av[rr].w, wv.w, acc[rr][ci]);
                }
            }
        }
        __syncthreads();   // everyone done reading vec
        float* L = vec;    // reuse as logits [64][65]
        #pragma unroll
        for (int rr = 0; rr < 4; ++rr)
            #pragma unroll
            for (int ci = 0; ci < 4; ++ci)
                L[(r0 + rr) * 65 + c0 + ci] = acc[rr][ci];
        __syncthreads();

        if (t < 64) {
            float mx = -1e30f;
            #pragma unroll 4
            for (int c = 0; c < 64; ++c) mx = fmaxf(mx, L[t * 65 + c]);
            float s = 0.0f;
            #pragma unroll 4
            for (int c = 0; c < 64; ++c) s += __expf(L[t * 65 + c] - mx);
            rmax_s[t] = mx;
            inv_s[t]  = 1.0f / s;
        }
        __syncthreads();

        #pragma unroll
        for (int rr = 0; rr < 4; ++rr) {
            int r = base + r0 + rr;
            float mx = rmax_s[r0 + rr], iv = inv_s[r0 + rr];
            float wv[4];
            #pragma unroll
            for (int ci = 0; ci < 4; ++ci)
                wv[ci] = __expf(L[(r0 + rr) * 65 + c0 + ci] - mx) * iv;
            if (r < MROWS) {
                ushort4 pk;
                pk.x = f2bf(wv[0]); pk.y = f2bf(wv[1]); pk.z = f2bf(wv[2]); pk.w = f2bf(wv[3]);
                *(ushort4*)(Wbuf + (size_t)r * CN + c0) = pk;
            } else {
                float4 f4; f4.x = wv[0]; f4.y = wv[1]; f4.z = wv[2]; f4.w = wv[3];
                *(float4*)(WTbuf + (size_t)(r - MROWS) * CN + c0) = f4;
            }
        }
    }
}

// ---------------- kernel 3: the scan (linear recurrence) + final read ----------------
__global__ __launch_bounds__(1024) void k_scan(
    const unsigned short* __restrict__ Ebuf, const unsigned short* __restrict__ Abuf,
    const unsigned short* __restrict__ Wbuf, const float* __restrict__ WTbuf,
    const float* __restrict__ rmem0, const float* __restrict__ wmem0,
    float* __restrict__ readbuf)
{
    const int t  = threadIdx.x;
    const int bx = blockIdx.x;          // 0..255
    const int m  = bx >> 7;
    const int b  = bx & 127;
    const int v  = t >> 3;
    const int ck = t & 7;
    const int c0 = ck * 8;

    const float* minit = (m == 0) ? rmem0 : wmem0;
    float mm[8];
    #pragma unroll
    for (int j = 0; j < 8; ++j) mm[j] = minit[v * CN + c0 + j];

    const size_t rb = (size_t)(m * BB * SS + b * SS);
    const unsigned short* Ep = Ebuf + rb * VD + v;
    const unsigned short* Ap = Abuf + rb * VD + v;
    const unsigned short* Wp = Wbuf + rb * CN + c0;

    for (int step = 0; step < SS; ++step) {
        float e = bflo((unsigned int)Ep[(size_t)step * VD]);
        float a = bflo((unsigned int)Ap[(size_t)step * VD]);
        uint4 wr = *(const uint4*)(Wp + (size_t)step * CN);
        float w[8];
        w[0] = bflo(wr.x); w[1] = bfhi(wr.x);
        w[2] = bflo(wr.y); w[3] = bfhi(wr.y);
        w[4] = bflo(wr.z); w[5] = bfhi(wr.z);
        w[6] = bflo(wr.w); w[7] = bfhi(wr.w);
        #pragma unroll
        for (int j = 0; j < 8; ++j) {
            float g = fmaf(-e, mm[j], a);        // a - e*m
            mm[j] = fmaf(w[j], g, mm[j]);        // m + w*(a - e*m)
        }
    }

    const float4* wt4 = (const float4*)(WTbuf + (size_t)b * CN + c0);
    float4 wa = wt4[0], wb = wt4[1];
    float p = 0.0f;
    p = fmaf(mm[0], wa.x, p); p = fmaf(mm[1], wa.y, p);
    p = fmaf(mm[2], wa.z, p); p = fmaf(mm[3], wa.w, p);
    p = fmaf(mm[4], wb.x, p); p = fmaf(mm[5], wb.y, p);
    p = fmaf(mm[6], wb.z, p); p = fmaf(mm[7], wb.w, p);
    p += __shfl_xor(p, 1);
    p += __shfl_xor(p, 2);
    p += __shfl_xor(p, 4);
    if (ck == 0) readbuf[(size_t)(m * BB + b) * VD + v] = p;
}

// ---------------- kernel 4: head ----------------
__global__ __launch_bounds__(128) void k_head(
    const float* __restrict__ readbuf, const int* __restrict__ tgt,
    const float* __restrict__ q_emb,
    const float* __restrict__ rsum_W, const float* __restrict__ rsum_b,
    const float* __restrict__ wsum_W, const float* __restrict__ wsum_b,
    const float* __restrict__ succ_W, const float* __restrict__ succ_b,
    const float* __restrict__ fail_W, const float* __restrict__ fail_b,
    const float* __restrict__ diff_W, const float* __restrict__ diff_b,
    const float* __restrict__ sig, float* __restrict__ out)
{
    __shared__ float xr[256], xw[256];
    __shared__ float red_s[6];
    const int j = threadIdx.x;
    const int b = blockIdx.x;
    const int tid_ = tgt[b];
    float qv = q_emb[(size_t)tid_ * KD + j];
    xr[j]        = readbuf[(size_t)b * VD + j];
    xr[128 + j]  = qv;
    xw[j]        = readbuf[(size_t)(BB + b) * VD + j];
    xw[128 + j]  = qv;
    __syncthreads();

    float rs = rsum_b[j], wv = wsum_b[j];
    const float* rw = rsum_W + (size_t)j * 256;
    const float* ww = wsum_W + (size_t)j * 256;
    #pragma unroll 4
    for (int k = 0; k < 256; ++k) {
        rs = fmaf(rw[k], xr[k], rs);
        wv = fmaf(ww[k], xw[k], wv);
    }
    float r_sum = tanhf(rs), w_sum = tanhf(wv);
    float ps = r_sum * succ_W[j];
    float pf = w_sum * fail_W[j];
    float pd = qv    * diff_W[j];
    for (int off = 1; off < 64; off <<= 1) {
        ps += __shfl_xor(ps, off);
        pf += __shfl_xor(pf, off);
        pd += __shfl_xor(pd, off);
    }
    int wid = j >> 6;
    if ((j & 63) == 0) { red_s[wid*3+0] = ps; red_s[wid*3+1] = pf; red_s[wid*3+2] = pd; }
    __syncthreads();
    if (j == 0) {
        float Ps = red_s[0] + red_s[3];
        float Pf = red_s[1] + red_s[4];
        float Pd = red_s[2] + red_s[5];
        float succ = tanhf(Ps + succ_b[0]);
        float fail = tanhf(Pf + fail_b[0]);
        float diff = tanhf(Pd + diff_b[0]);
        out[b] = succ * sig[0] + fail * sig[1] - 2.0f * diff;
    }
}

extern "C" void kernel_launch(void* const* d_in, const int* in_sizes, int n_in,
                              void* d_out, int out_size, void* d_ws, size_t ws_size,
                              hipStream_t stream) {
    const int*   ri      = (const int*)d_in[0];
    const int*   wi      = (const int*)d_in[1];
    const int*   tgt     = (const int*)d_in[2];
    const float* q_emb   = (const float*)d_in[3];
    const float* i_emb   = (const float*)d_in[4];
    const float* key_W   = (const float*)d_in[5];
    const float* erase_W = (const float*)d_in[6];
    const float* erase_b = (const float*)d_in[7];
    const float* add_W   = (const float*)d_in[8];
    const float* add_b   = (const float*)d_in[9];
    const float* rsum_W  = (const float*)d_in[10];
    const float* rsum_b  = (const float*)d_in[11];
    const float* wsum_W  = (const float*)d_in[12];
    const float* wsum_b  = (const float*)d_in[13];
    const float* succ_W  = (const float*)d_in[14];
    const float* succ_b  = (const float*)d_in[15];
    const float* fail_W  = (const float*)d_in[16];
    const float* fail_b  = (const float*)d_in[17];
    const float* diff_W  = (const float*)d_in[18];
    const float* diff_b  = (const float*)d_in[19];
    const float* rmem0   = (const float*)d_in[20];
    const float* wmem0   = (const float*)d_in[21];

    char* ws = (char*)d_ws;
    unsigned short* Ebuf  = (unsigned short*)(ws + 0);          //  8,388,608 B
    unsigned short* Abuf  = (unsigned short*)(ws + 8388608);    //  8,388,608 B
    unsigned short* Wbuf  = (unsigned short*)(ws + 16777216);   //  4,194,304 B
    float*          WTbuf = (float*)(ws + 20971520);            //     32,768 B
    float*          readbuf = (float*)(ws + 21004288);          //    131,072 B
    float*          sig   = (float*)(ws + 21135360);            //          8 B
    float*          out   = (float*)d_out;

    hipLaunchKernelGGL(k_count, dim3(1), dim3(256), 0, stream, ri, wi, sig);
    hipLaunchKernelGGL(k_pre, dim3(514), dim3(256), 0, stream,
        ri, wi, tgt, q_emb, i_emb, key_W, erase_W, erase_b, add_W, add_b,
        Ebuf, Abuf, Wbuf, WTbuf);
    hipLaunchKernelGGL(k_scan, dim3(256), dim3(1024), 0, stream,
        Ebuf, Abuf, Wbuf, WTbuf, rmem0, wmem0, readbuf);
    hipLaunchKernelGGL(k_head, dim3(128), dim3(128), 0, stream,
        readbuf, tgt, q_emb, rsum_W, rsum_b, wsum_W, wsum_b,
        succ_W, succ_b, fail_W, fail_b, diff_W, diff_b, sig, out);
}

// Round 2
// 75.516 us; speedup vs baseline: 2.9552x; 2.9552x over previous
//
#include <hip/hip_runtime.h>
#include <hip/hip_bf16.h>

#define BB 128      // batch
#define SS 128      // seq len
#define VD 128      // VALUE_DIM
#define CN 64       // CONCEPT_NUM
#define KD 128      // KEY_DIM
#define QN 10000
#define MROWS (2*BB*SS)       // 32768
#define MTOT  (MROWS + BB)    // 32896

typedef __attribute__((ext_vector_type(8))) short bf16x8;
typedef __attribute__((ext_vector_type(4))) float f32x4;
typedef __attribute__((ext_vector_type(2))) float f32x2;

__device__ __forceinline__ float bflo(unsigned int u) { return __uint_as_float(u << 16); }
__device__ __forceinline__ unsigned short f2bf(float f) {
    unsigned int x = __float_as_uint(f);
    return (unsigned short)((x + 0x7fffu + ((x >> 16) & 1u)) >> 16);
}
__device__ __forceinline__ unsigned int pk2(float lo, float hi) {
    return (unsigned int)f2bf(lo) | ((unsigned int)f2bf(hi) << 16);
}
__device__ __forceinline__ f32x2 unpk(unsigned int u) {
    union { unsigned int u2[2]; f32x2 f; } x;
    x.u2[0] = u << 16; x.u2[1] = u & 0xffff0000u;
    return x.f;
}
__device__ __forceinline__ float fast_tanh(float x) {
    float e = __expf(2.0f * x);
    return 1.0f - 2.0f / (e + 1.0f);
}
__device__ __forceinline__ float fast_sig(float x) {
    return 1.0f / (1.0f + __expf(-x));
}

// ---------------- kernel 1: success/failure counts -> sigmoid ----------------
__global__ void k_count(const int* __restrict__ ri, const int* __restrict__ wi,
                        float* __restrict__ sig) {
    __shared__ int sr_s[4], sw_s[4];
    int t = threadIdx.x;
    int sr = 0, sw = 0;
    for (int i = t; i < BB*SS; i += 256) { sr += (ri[i] >= 1); sw += (wi[i] >= 1); }
    for (int off = 1; off < 64; off <<= 1) { sr += __shfl_xor(sr, off); sw += __shfl_xor(sw, off); }
    int wid = t >> 6;
    if ((t & 63) == 0) { sr_s[wid] = sr; sw_s[wid] = sw; }
    __syncthreads();
    if (t == 0) {
        int SR = sr_s[0]+sr_s[1]+sr_s[2]+sr_s[3];
        int SW = sw_s[0]+sw_s[1]+sw_s[2]+sw_s[3];
        sig[0] = 1.0f / (1.0f + __expf(-(float)SR));
        sig[1] = 1.0f / (1.0f + __expf(-(float)SW));
    }
}

// ---------------- kernel 1b: pack weights (erase|add|key) into MFMA B-fragment order ----------------
// Bfrag[(g*4+kt)*64 + lane] = 8 bf16: W[n][k], n = g*16 + (lane&15), k = kt*32 + (lane>>4)*8 + i
__global__ __launch_bounds__(64) void k_wcvt(
    const float* __restrict__ erase_W, const float* __restrict__ add_W,
    const float* __restrict__ key_W, unsigned short* __restrict__ Bfrag)
{
    const int bid = blockIdx.x;          // g*4 + kt, 0..79
    const int l = threadIdx.x;
    const int n = (bid >> 2) * 16 + (l & 15);
    const int k0 = (bid & 3) * 32 + (l >> 4) * 8;
    const float* src;
    if (n < 128)      src = erase_W + (size_t)n * KD + k0;
    else if (n < 256) src = add_W + (size_t)(n - 128) * KD + k0;
    else              src = key_W + (size_t)(n - 256) * KD + k0;
    float4 fa = ((const float4*)src)[0];
    float4 fb = ((const float4*)src)[1];
    uint4 o = make_uint4(pk2(fa.x, fa.y), pk2(fa.z, fa.w), pk2(fb.x, fb.y), pk2(fb.z, fb.w));
    *(uint4*)(Bfrag + ((size_t)bid * 64 + l) * 8) = o;
}

// ---------------- kernel 2: MFMA precompute of E, A (bf16) and W (bf16) / WT (f32) ----------------
__global__ __launch_bounds__(256) void k_mfma(
    const int* __restrict__ ri, const int* __restrict__ wi, const int* __restrict__ tgt,
    const float* __restrict__ q_emb, const float* __restrict__ i_emb,
    const float* __restrict__ erase_b, const float* __restrict__ add_b,
    const unsigned short* __restrict__ Bfrag,
    unsigned short* __restrict__ Ebuf, unsigned short* __restrict__ Abuf,
    unsigned short* __restrict__ Wbuf, float* __restrict__ WTbuf)
{
    __shared__ __align__(16) char shA[32 * 256];      // Xi bf16, swizzled
    __shared__ __align__(16) char shB[32 * 68 * 4];   // Xq bf16 swizzled, then logits f32 [32][68]
    __shared__ int id_s[32], ir_s[32];

    const int t = threadIdx.x;
    const int lane = t & 63;
    const int w = t >> 6;
    const int base = blockIdx.x * 32;
    const bool ea = (base < MROWS);

    if (t < 32) {
        int r = base + t;
        int irow = 0, qid;
        if (r < MROWS) {
            int m = r >> 14;
            int idx = r & 16383;
            int inter = (m == 0) ? ri[idx] : wi[idx];
            irow = inter;
            qid = (inter > QN) ? inter - QN : inter;
        } else {
            qid = tgt[r - MROWS];
        }
        id_s[t] = qid; ir_s[t] = irow;
    }
    __syncthreads();

    // stage Xq (always) and Xi (if E/A block), bf16 + XOR-swizzle (byte ^= (row&7)<<4)
    {
        const int r = t >> 3, o = t & 7;
        const int bb = r * 256 + o * 32;
        const int sw = (r & 7) << 4;
        {
            const float* src = q_emb + (size_t)id_s[r] * KD + o * 16;
            float4 f0 = ((const float4*)src)[0];
            float4 f1 = ((const float4*)src)[1];
            float4 f2 = ((const float4*)src)[2];
            float4 f3 = ((const float4*)src)[3];
            *(uint4*)(shB + (bb ^ sw))        = make_uint4(pk2(f0.x,f0.y), pk2(f0.z,f0.w), pk2(f1.x,f1.y), pk2(f1.z,f1.w));
            *(uint4*)(shB + ((bb + 16) ^ sw)) = make_uint4(pk2(f2.x,f2.y), pk2(f2.z,f2.w), pk2(f3.x,f3.y), pk2(f3.z,f3.w));
        }
        if (ea) {
            const float* src = i_emb + (size_t)ir_s[r] * KD + o * 16;
            float4 f0 = ((const float4*)src)[0];
            float4 f1 = ((const float4*)src)[1];
            float4 f2 = ((const float4*)src)[2];
            float4 f3 = ((const float4*)src)[3];
            *(uint4*)(shA + (bb ^ sw))        = make_uint4(pk2(f0.x,f0.y), pk2(f0.z,f0.w), pk2(f1.x,f1.y), pk2(f1.z,f1.w));
            *(uint4*)(shA + ((bb + 16) ^ sw)) = make_uint4(pk2(f2.x,f2.y), pk2(f2.z,f2.w), pk2(f3.x,f3.y), pk2(f3.z,f3.w));
        }
    }
    __syncthreads();

    // ---- key logits GEMM: Xq(32x128) x key_W^T(128x64), wave w owns cols w*16..w*16+15 ----
    const int rowl = lane & 15;
    const int kb16 = (lane >> 4) * 16;

    bf16x8 afQ[2][4];
    #pragma unroll
    for (int mt = 0; mt < 2; ++mt)
        #pragma unroll
        for (int kt = 0; kt < 4; ++kt) {
            int row = mt * 16 + rowl;
            int addr = (row * 256 + kt * 64 + kb16) ^ ((row & 7) << 4);
            afQ[mt][kt] = *(const bf16x8*)(shB + addr);
        }

    f32x4 accK0 = {0.f,0.f,0.f,0.f}, accK1 = {0.f,0.f,0.f,0.f};
    {
        const int gk = 16 + w;
        #pragma unroll
        for (int kt = 0; kt < 4; ++kt) {
            bf16x8 bf = *(const bf16x8*)(Bfrag + ((size_t)(gk * 4 + kt) * 64 + lane) * 8);
            accK0 = __builtin_amdgcn_mfma_f32_16x16x32_bf16(afQ[0][kt], bf, accK0, 0, 0, 0);
            accK1 = __builtin_amdgcn_mfma_f32_16x16x32_bf16(afQ[1][kt], bf, accK1, 0, 0, 0);
        }
    }
    __syncthreads();   // done reading shB (Xq)

    // write logits to shB as f32 [32][68]
    {
        float* L = (float*)shB;
        const int col = w * 16 + rowl;
        const int rb4 = (lane >> 4) * 4;
        #pragma unroll
        for (int rr = 0; rr < 4; ++rr) L[(rb4 + rr) * 68 + col] = accK0[rr];
        #pragma unroll
        for (int rr = 0; rr < 4; ++rr) L[(16 + rb4 + rr) * 68 + col] = accK1[rr];
    }
    __syncthreads();

    // softmax over 64 cols: 8 threads per row (8 cols each), shfl-reduce within 8-lane group
    {
        const float* L = (const float*)shB;
        const int rr = t >> 3, q = t & 7;
        float4 va = *(const float4*)(L + rr * 68 + q * 8);
        float4 vb = *(const float4*)(L + rr * 68 + q * 8 + 4);
        float mx = fmaxf(fmaxf(fmaxf(va.x, va.y), fmaxf(va.z, va.w)),
                         fmaxf(fmaxf(vb.x, vb.y), fmaxf(vb.z, vb.w)));
        #pragma unroll
        for (int off = 1; off < 8; off <<= 1) mx = fmaxf(mx, __shfl_xor(mx, off));
        float e0 = __expf(va.x - mx), e1 = __expf(va.y - mx), e2 = __expf(va.z - mx), e3 = __expf(va.w - mx);
        float e4 = __expf(vb.x - mx), e5 = __expf(vb.y - mx), e6 = __expf(vb.z - mx), e7 = __expf(vb.w - mx);
        float s = e0 + e1 + e2 + e3 + e4 + e5 + e6 + e7;
        #pragma unroll
        for (int off = 1; off < 8; off <<= 1) s += __shfl_xor(s, off);
        float inv = 1.0f / s;
        int R = base + rr;
        if (R < MROWS) {
            uint4 o = make_uint4(pk2(e0*inv, e1*inv), pk2(e2*inv, e3*inv),
                                 pk2(e4*inv, e5*inv), pk2(e6*inv, e7*inv));
            *(uint4*)(Wbuf + (size_t)R * CN + q * 8) = o;
        } else {
            float* dst = WTbuf + (size_t)(R - MROWS) * CN + q * 8;
            *(float4*)dst       = make_float4(e0*inv, e1*inv, e2*inv, e3*inv);
            *(float4*)(dst + 4) = make_float4(e4*inv, e5*inv, e6*inv, e7*inv);
        }
    }

    // ---- E/A GEMM: Xi(32x128) x [erase;add]^T(128x256); wave w owns g = w, w+4, w+8, w+12 ----
    if (ea) {
        bf16x8 afI[2][4];
        #pragma unroll
        for (int mt = 0; mt < 2; ++mt)
            #pragma unroll
            for (int kt = 0; kt < 4; ++kt) {
                int row = mt * 16 + rowl;
                int addr = (row * 256 + kt * 64 + kb16) ^ ((row & 7) << 4);
                afI[mt][kt] = *(const bf16x8*)(shA + addr);
            }

        const int rb4 = (lane >> 4) * 4;
        #pragma unroll
        for (int gi = 0; gi < 4; ++gi) {
            const int g = w + gi * 4;            // 0..15
            f32x4 a0 = {0.f,0.f,0.f,0.f}, a1 = {0.f,0.f,0.f,0.f};
            #pragma unroll
            for (int kt = 0; kt < 4; ++kt) {
                bf16x8 bf = *(const bf16x8*)(Bfrag + ((size_t)(g * 4 + kt) * 64 + lane) * 8);
                a0 = __builtin_amdgcn_mfma_f32_16x16x32_bf16(afI[0][kt], bf, a0, 0, 0, 0);
                a1 = __builtin_amdgcn_mfma_f32_16x16x32_bf16(afI[1][kt], bf, a1, 0, 0, 0);
            }
            const bool isE = (g < 8);
            const int cc = (g & 7) * 16 + rowl;  // col within E or A (0..127)
            const float bv = isE ? erase_b[cc] : add_b[cc];
            unsigned short* dst = isE ? Ebuf : Abuf;
            #pragma unroll
            for (int mt = 0; mt < 2; ++mt) {
                f32x4 av = mt ? a1 : a0;
                #pragma unroll
                for (int rr = 0; rr < 4; ++rr) {
                    float x = av[rr] + bv;
                    float y = isE ? fast_sig(x) : fast_tanh(x);
                    dst[(size_t)(base + mt * 16 + rb4 + rr) * VD + cc] = f2bf(y);
                }
            }
        }
    }
}

// ---------------- kernel 3: the scan (linear recurrence) + final read ----------------
__global__ __launch_bounds__(1024) void k_scan(
    const unsigned short* __restrict__ Ebuf, const unsigned short* __restrict__ Abuf,
    const unsigned short* __restrict__ Wbuf, const float* __restrict__ WTbuf,
    const float* __restrict__ rmem0, const float* __restrict__ wmem0,
    float* __restrict__ readbuf)
{
    __shared__ float psum[8 * 128];
    const int t  = threadIdx.x;
    const int bx = blockIdx.x;          // 0..255
    const int m  = bx >> 7;
    const int b  = bx & 127;
    const int ck = t >> 7;              // 0..7  (wave-uniform)
    const int v  = t & 127;             // coalesced across lanes
    const int c0 = ck * 8;

    const float* minit = (m == 0) ? rmem0 : wmem0;
    f32x2 mm[4];
    #pragma unroll
    for (int j = 0; j < 4; ++j) {
        mm[j].x = minit[v * CN + c0 + 2*j];
        mm[j].y = minit[v * CN + c0 + 2*j + 1];
    }

    const size_t rb = (size_t)(m * BB + b) * SS;
    const unsigned short* Ep = Ebuf + rb * VD + v;
    const unsigned short* Ap = Abuf + rb * VD + v;
    const unsigned short* Wp = Wbuf + rb * CN + c0;

    #pragma unroll 2
    for (int s = 0; s < SS; ++s) {
        float e = bflo((unsigned int)Ep[(size_t)s * VD]);
        float a = bflo((unsigned int)Ap[(size_t)s * VD]);
        uint4 wr = *(const uint4*)(Wp + (size_t)s * CN);   // wave-uniform broadcast
        f32x2 w0 = unpk(wr.x), w1 = unpk(wr.y), w2 = unpk(wr.z), w3 = unpk(wr.w);
        f32x2 ev = {e, e}, av = {a, a};
        f32x2 g;
        g = av - ev * mm[0]; mm[0] += w0 * g;
        g = av - ev * mm[1]; mm[1] += w1 * g;
        g = av - ev * mm[2]; mm[2] += w2 * g;
        g = av - ev * mm[3]; mm[3] += w3 * g;
    }

    const float* wt = WTbuf + (size_t)b * CN + c0;
    float4 wa = *(const float4*)wt;
    float4 wb = *(const float4*)(wt + 4);
    float p = 0.0f;
    p = fmaf(mm[0].x, wa.x, p); p = fmaf(mm[0].y, wa.y, p);
    p = fmaf(mm[1].x, wa.z, p); p = fmaf(mm[1].y, wa.w, p);
    p = fmaf(mm[2].x, wb.x, p); p = fmaf(mm[2].y, wb.y, p);
    p = fmaf(mm[3].x, wb.z, p); p = fmaf(mm[3].y, wb.w, p);
    psum[ck * 128 + v] = p;
    __syncthreads();
    if (t < 128) {
        float s = 0.0f;
        #pragma unroll
        for (int j = 0; j < 8; ++j) s += psum[j * 128 + t];
        readbuf[(size_t)(m * BB + b) * VD + t] = s;
    }
}

// ---------------- kernel 4: head ----------------
__global__ __launch_bounds__(128) void k_head(
    const float* __restrict__ readbuf, const int* __restrict__ tgt,
    const float* __restrict__ q_emb,
    const float* __restrict__ rsum_W, const float* __restrict__ rsum_b,
    const float* __restrict__ wsum_W, const float* __restrict__ wsum_b,
    const float* __restrict__ succ_W, const float* __restrict__ succ_b,
    const float* __restrict__ fail_W, const float* __restrict__ fail_b,
    const float* __restrict__ diff_W, const float* __restrict__ diff_b,
    const float* __restrict__ sig, float* __restrict__ out)
{
    __shared__ float xr[256], xw[256];
    __shared__ float red_s[6];
    const int j = threadIdx.x;
    const int b = blockIdx.x;
    const int tid_ = tgt[b];
    float qv = q_emb[(size_t)tid_ * KD + j];
    xr[j]        = readbuf[(size_t)b * VD + j];
    xr[128 + j]  = qv;
    xw[j]        = readbuf[(size_t)(BB + b) * VD + j];
    xw[128 + j]  = qv;
    __syncthreads();

    float rs = rsum_b[j], wv = wsum_b[j];
    const float* rw = rsum_W + (size_t)j * 256;
    const float* ww = wsum_W + (size_t)j * 256;
    #pragma unroll 4
    for (int k = 0; k < 256; ++k) {
        rs = fmaf(rw[k], xr[k], rs);
        wv = fmaf(ww[k], xw[k], wv);
    }
    float r_sum = tanhf(rs), w_sum = tanhf(wv);
    float ps = r_sum * succ_W[j];
    float pf = w_sum * fail_W[j];
    float pd = qv    * diff_W[j];
    for (int off = 1; off < 64; off <<= 1) {
        ps += __shfl_xor(ps, off);
        pf += __shfl_xor(pf, off);
        pd += __shfl_xor(pd, off);
    }
    int wid = j >> 6;
    if ((j & 63) == 0) { red_s[wid*3+0] = ps; red_s[wid*3+1] = pf; red_s[wid*3+2] = pd; }
    __syncthreads();
    if (j == 0) {
        float Ps = red_s[0] + red_s[3];
        float Pf = red_s[1] + red_s[4];
        float Pd = red_s[2] + red_s[5];
        float succ = tanhf(Ps + succ_b[0]);
        float fail = tanhf(Pf + fail_b[0]);
        float diff = tanhf(Pd + diff_b[0]);
        out[b] = succ * sig[0] + fail * sig[1] - 2.0f * diff;
    }
}

extern "C" void kernel_launch(void* const* d_in, const int* in_sizes, int n_in,
                              void* d_out, int out_size, void* d_ws, size_t ws_size,
                              hipStream_t stream) {
    const int*   ri      = (const int*)d_in[0];
    const int*   wi      = (const int*)d_in[1];
    const int*   tgt     = (const int*)d_in[2];
    const float* q_emb   = (const float*)d_in[3];
    const float* i_emb   = (const float*)d_in[4];
    const float* key_W   = (const float*)d_in[5];
    const float* erase_W = (const float*)d_in[6];
    const float* erase_b = (const float*)d_in[7];
    const float* add_W   = (const float*)d_in[8];
    const float* add_b   = (const float*)d_in[9];
    const float* rsum_W  = (const float*)d_in[10];
    const float* rsum_b  = (const float*)d_in[11];
    const float* wsum_W  = (const float*)d_in[12];
    const float* wsum_b  = (const float*)d_in[13];
    const float* succ_W  = (const float*)d_in[14];
    const float* succ_b  = (const float*)d_in[15];
    const float* fail_W  = (const float*)d_in[16];
    const float* fail_b  = (const float*)d_in[17];
    const float* diff_W  = (const float*)d_in[18];
    const float* diff_b  = (const float*)d_in[19];
    const float* rmem0   = (const float*)d_in[20];
    const float* wmem0   = (const float*)d_in[21];

    char* ws = (char*)d_ws;
    unsigned short* Ebuf    = (unsigned short*)(ws + 0);          //  8,388,608 B
    unsigned short* Abuf    = (unsigned short*)(ws + 8388608);    //  8,388,608 B
    unsigned short* Wbuf    = (unsigned short*)(ws + 16777216);   //  4,194,304 B
    float*          WTbuf   = (float*)(ws + 20971520);            //     32,768 B
    float*          readbuf = (float*)(ws + 21004288);            //    131,072 B
    unsigned short* Bfrag   = (unsigned short*)(ws + 21004288);   //  81,920 B (aliases readbuf:
                                                                  //  written by k_wcvt, read by k_mfma,
                                                                  //  then dead before k_scan writes readbuf)
    float*          sig     = (float*)(ws + 21135360);            //          8 B
    float*          out     = (float*)d_out;

    hipLaunchKernelGGL(k_count, dim3(1), dim3(256), 0, stream, ri, wi, sig);
    hipLaunchKernelGGL(k_wcvt, dim3(80), dim3(64), 0, stream,
        erase_W, add_W, key_W, Bfrag);
    hipLaunchKernelGGL(k_mfma, dim3(1028), dim3(256), 0, stream,
        ri, wi, tgt, q_emb, i_emb, erase_b, add_b, Bfrag,
        Ebuf, Abuf, Wbuf, WTbuf);
    hipLaunchKernelGGL(k_scan, dim3(256), dim3(1024), 0, stream,
        Ebuf, Abuf, Wbuf, WTbuf, rmem0, wmem0, readbuf);
    hipLaunchKernelGGL(k_head, dim3(128), dim3(128), 0, stream,
        readbuf, tgt, q_emb, rsum_W, rsum_b, wsum_W, wsum_b,
        succ_W, succ_b, fail_W, fail_b, diff_W, diff_b, sig, out);
}